// Round 2
// baseline (18591.679 us; speedup 1.0000x reference)
//
#include <hip/hip_runtime.h>
#include <hip/hip_bf16.h>
#include <math.h>

typedef __hip_bfloat16 bf16;
typedef __attribute__((ext_vector_type(8))) __bf16 bhalf8;
typedef __attribute__((ext_vector_type(4))) float f32x4;

#define T_SEQ  1024
#define DIM    1024
#define NH     16
#define DH     64
#define FFDIM  4096
#define BATCH  8
#define NLAYER 8
#define VOCAB  2048
#define NTOK   (BATCH * T_SEQ)

// ---------------- weight convert: f32 -> bf16, fused per layer ----------------
// dst layout (elements): [0,1M) Wq | [1M,2M) Wk | [2M,3M) Wv | [3M,4M) Wo |
//                        [4M,8M) W1 | [8M,12M) W2      (1M = 1048576 = D*D)
__global__ __launch_bounds__(256) void cvt_layer_kernel(
    const float* __restrict__ Wq, const float* __restrict__ Wk,
    const float* __restrict__ Wv, const float* __restrict__ Wo,
    const float* __restrict__ W1, const float* __restrict__ W2,
    bf16* __restrict__ dst) {
  size_t i = ((size_t)blockIdx.x * 256 + threadIdx.x) * 4;
  const float* src;
  size_t off;
  if (i < (1ull << 22)) {                       // 4M: qkvo
    int which = (int)(i >> 20);
    off = i & ((1ull << 20) - 1);
    src = which == 0 ? Wq : which == 1 ? Wk : which == 2 ? Wv : Wo;
  } else if (i < (8ull << 20)) { src = W1; off = i - (4ull << 20); }
  else                         { src = W2; off = i - (8ull << 20); }
  float4 v = *(const float4*)(src + off);
  __hip_bfloat162 lo = __float22bfloat162_rn(make_float2(v.x, v.y));
  __hip_bfloat162 hi = __float22bfloat162_rn(make_float2(v.z, v.w));
  *(__hip_bfloat162*)&dst[i] = lo;
  *(__hip_bfloat162*)&dst[i + 2] = hi;
}

__global__ __launch_bounds__(256) void cvt_kernel(
    const float* __restrict__ src, bf16* __restrict__ dst) {
  size_t i = ((size_t)blockIdx.x * 256 + threadIdx.x) * 4;
  float4 v = *(const float4*)(src + i);
  __hip_bfloat162 lo = __float22bfloat162_rn(make_float2(v.x, v.y));
  __hip_bfloat162 hi = __float22bfloat162_rn(make_float2(v.z, v.w));
  *(__hip_bfloat162*)&dst[i] = lo;
  *(__hip_bfloat162*)&dst[i + 2] = hi;
}

// ---------------- embedding: x = tok_emb[idx] + pos_emb (f32) ----------------
__global__ __launch_bounds__(256) void embed_kernel(
    const int* __restrict__ idx, const float* __restrict__ tok,
    const float* __restrict__ pos, float* __restrict__ x) {
  int row = blockIdx.x;                 // b*T + t
  int t = row & (T_SEQ - 1);
  int tk = idx[row];
  int c = threadIdx.x * 4;
  float4 tv = *(const float4*)(tok + (size_t)tk * DIM + c);
  float4 pv = *(const float4*)(pos + (size_t)t * DIM + c);
  float4 o;
  o.x = tv.x + pv.x; o.y = tv.y + pv.y; o.z = tv.z + pv.z; o.w = tv.w + pv.w;
  *(float4*)(x + (size_t)row * DIM + c) = o;
}

// ---------------- layernorm: f32 in -> bf16 out ----------------
__global__ __launch_bounds__(256) void ln_kernel(
    const float* __restrict__ x, const float* __restrict__ g,
    const float* __restrict__ b, bf16* __restrict__ out) {
  int row = blockIdx.x;
  int c = threadIdx.x * 4;
  const float* xr = x + (size_t)row * DIM;
  float4 v = *(const float4*)&xr[c];
  float s = v.x + v.y + v.z + v.w;
  float ss = v.x * v.x + v.y * v.y + v.z * v.z + v.w * v.w;
#pragma unroll
  for (int off = 32; off > 0; off >>= 1) {
    s += __shfl_xor(s, off, 64);
    ss += __shfl_xor(ss, off, 64);
  }
  __shared__ float red[4][2];
  int w = threadIdx.x >> 6;
  if ((threadIdx.x & 63) == 0) { red[w][0] = s; red[w][1] = ss; }
  __syncthreads();
  float S = red[0][0] + red[1][0] + red[2][0] + red[3][0];
  float SS = red[0][1] + red[1][1] + red[2][1] + red[3][1];
  float mean = S * (1.0f / DIM);
  float var = SS * (1.0f / DIM) - mean * mean;
  float rstd = rsqrtf(var + 1e-5f);
  bf16* orow = out + (size_t)row * DIM + c;
  float vv[4] = {v.x, v.y, v.z, v.w};
#pragma unroll
  for (int i = 0; i < 4; ++i)
    orow[i] = __float2bfloat16((vv[i] - mean) * rstd * g[c + i] + b[c + i]);
}

__device__ __forceinline__ float gelu_f(float x) {
  return 0.5f * x * (1.0f + erff(x * 0.70710678118654752f));
}

// ---------------- GEMM: C[M,N] = A[M,K] @ B[K,N] + bias ----------------
// EPI: 0 = store bf16, 1 = gelu->bf16, 2 = add into f32 residual, 3 = store f32
template <int EPI>
__global__ __launch_bounds__(256) void gemm_kernel(
    const bf16* __restrict__ A, const bf16* __restrict__ B,
    const float* __restrict__ bias, void* __restrict__ outp,
    float* __restrict__ res, int M, int N, int K, int lda, int ldb, int ldc) {
  __shared__ ushort As[128][32];    // A tile, row-major
  __shared__ ushort Bs[32][130];    // B tile, pad to 65 words/row: conflict-free col reads
  int m0 = blockIdx.y * 128, n0 = blockIdx.x * 128;
  int t = threadIdx.x;
  int lane = t & 63, w = t >> 6;
  int wm = (w & 1) * 64, wn = (w >> 1) * 64;
  int ml = lane & 15, quad = lane >> 4;
  int q8 = quad * 8;

  f32x4 acc[4][4];
#pragma unroll
  for (int i = 0; i < 4; ++i)
#pragma unroll
    for (int j = 0; j < 4; ++j) acc[i][j] = (f32x4){0.f, 0.f, 0.f, 0.f};

  for (int k0 = 0; k0 < K; k0 += 32) {
    __syncthreads();
#pragma unroll
    for (int i = 0; i < 2; ++i) {   // stage A: 128x32
      int c = t + i * 256;
      int r = c >> 2, cc = (c & 3) * 8;
      *(uint4*)&As[r][cc] = *(const uint4*)(A + (size_t)(m0 + r) * lda + k0 + cc);
    }
#pragma unroll
    for (int i = 0; i < 2; ++i) {   // stage B: 32x128
      int c = t + i * 256;
      int r = c >> 4, cc = (c & 15) * 8;
      uint4 dv = *(const uint4*)(B + (size_t)(k0 + r) * ldb + n0 + cc);
      uint* dst = (uint*)&Bs[r][cc];
      const uint* sp = (const uint*)&dv;
      dst[0] = sp[0]; dst[1] = sp[1]; dst[2] = sp[2]; dst[3] = sp[3];
    }
    __syncthreads();
    bhalf8 af[4], bfr[4];
#pragma unroll
    for (int mt = 0; mt < 4; ++mt)
      af[mt] = *(const bhalf8*)&As[wm + mt * 16 + ml][q8];
#pragma unroll
    for (int nt = 0; nt < 4; ++nt) {
      int col = wn + nt * 16 + ml;
#pragma unroll
      for (int j = 0; j < 8; ++j)
        bfr[nt][j] = *(const __bf16*)&Bs[q8 + j][col];
    }
#pragma unroll
    for (int mt = 0; mt < 4; ++mt)
#pragma unroll
      for (int nt = 0; nt < 4; ++nt)
        acc[mt][nt] = __builtin_amdgcn_mfma_f32_16x16x32_bf16(
            af[mt], bfr[nt], acc[mt][nt], 0, 0, 0);
  }
  // epilogue: C/D layout col=lane&15, row=quad*4+r  (m89-verified)
#pragma unroll
  for (int nt = 0; nt < 4; ++nt) {
    int col = n0 + wn + nt * 16 + ml;
    float bv = bias[col];
#pragma unroll
    for (int mt = 0; mt < 4; ++mt) {
#pragma unroll
      for (int r = 0; r < 4; ++r) {
        int row = m0 + wm + mt * 16 + quad * 4 + r;
        float val = acc[mt][nt][r] + bv;
        if (EPI == 1) val = gelu_f(val);
        if (EPI == 2)
          res[(size_t)row * ldc + col] += val;
        else if (EPI == 3)
          ((float*)outp)[(size_t)row * ldc + col] = val;
        else
          ((bf16*)outp)[(size_t)row * ldc + col] = __float2bfloat16(val);
      }
    }
  }
}

// ---------------- flash-style causal attention (vector, f32 accum) -----
// grid: (T/64, H, B); 4 waves/block; wave w handles q-rows q0+16w..q0+16w+15
__global__ __launch_bounds__(256) void attn_kernel(
    const bf16* __restrict__ Q, const bf16* __restrict__ K,
    const bf16* __restrict__ V, bf16* __restrict__ Y) {
  int w = threadIdx.x >> 6, lane = threadIdx.x & 63;
  int q0 = blockIdx.x * 64;
  int h = blockIdx.y, b = blockIdx.z;
  __shared__ float Qs[64][65];
  __shared__ ushort Ks[64][66];   // pad 66 -> 33 words/row: conflict-free row & col access
  __shared__ ushort Vs[64][66];
  __shared__ float Ps[4][64];
  size_t base = ((size_t)b * T_SEQ) * DIM + (size_t)h * DH;
  int tr = threadIdx.x >> 2, tc = (threadIdx.x & 3) * 16;
  {
    const bf16* src = Q + base + (size_t)(q0 + tr) * DIM + tc;
#pragma unroll
    for (int i = 0; i < 16; ++i)
      Qs[tr][tc + i] = __bfloat162float(src[i]) * 0.125f;  // 1/sqrt(DH)
  }
  float O[16], m_r[16], l_r[16];
#pragma unroll
  for (int r = 0; r < 16; ++r) { O[r] = 0.f; m_r[r] = -1e30f; l_r[r] = 0.f; }
  int rbase = w * 16;
  int nkb = (q0 >> 6) + 1;
  for (int kb = 0; kb < nkb; ++kb) {
    __syncthreads();
    {
      const bf16* ksrc = K + base + (size_t)(kb * 64 + tr) * DIM + tc;
      const bf16* vsrc = V + base + (size_t)(kb * 64 + tr) * DIM + tc;
      uint4 k1 = *(const uint4*)(ksrc);
      uint4 k2 = *(const uint4*)(ksrc + 8);
      uint4 v1 = *(const uint4*)(vsrc);
      uint4 v2 = *(const uint4*)(vsrc + 8);
      uint* kd = (uint*)&Ks[tr][tc];
      uint* vd = (uint*)&Vs[tr][tc];
      const uint* p;
      p = (const uint*)&k1; kd[0]=p[0]; kd[1]=p[1]; kd[2]=p[2]; kd[3]=p[3];
      p = (const uint*)&k2; kd[4]=p[0]; kd[5]=p[1]; kd[6]=p[2]; kd[7]=p[3];
      p = (const uint*)&v1; vd[0]=p[0]; vd[1]=p[1]; vd[2]=p[2]; vd[3]=p[3];
      p = (const uint*)&v2; vd[4]=p[0]; vd[5]=p[1]; vd[6]=p[2]; vd[7]=p[3];
    }
    __syncthreads();
    bool diag = (kb == (q0 >> 6));
#pragma unroll
    for (int r = 0; r < 16; ++r) {
      int qrl = rbase + r;
      const float* qr = Qs[qrl];
      float acc = 0.f;
#pragma unroll
      for (int d = 0; d < 64; d += 2) {
        float2 kf = __bfloat1622float2(*(const __hip_bfloat162*)&Ks[lane][d]);
        acc += qr[d] * kf.x + qr[d + 1] * kf.y;
      }
      float s = (!diag || (lane <= qrl)) ? acc : -1e30f;
      float mx = s;
#pragma unroll
      for (int off = 32; off > 0; off >>= 1) mx = fmaxf(mx, __shfl_xor(mx, off, 64));
      float mnew = fmaxf(m_r[r], mx);
      float alpha = __expf(m_r[r] - mnew);
      float p = __expf(s - mnew);                   // masked -> exp(-huge) = 0
      float rs = p;
#pragma unroll
      for (int off = 32; off > 0; off >>= 1) rs += __shfl_xor(rs, off, 64);
      l_r[r] = l_r[r] * alpha + rs;
      m_r[r] = mnew;
      Ps[w][lane] = p;                              // same-wave LDS, DS ops in-order
      float o = O[r] * alpha;
#pragma unroll 4
      for (int j = 0; j < 64; ++j)
        o += Ps[w][j] * __bfloat162float(*(const bf16*)&Vs[j][lane]);
      O[r] = o;
    }
  }
#pragma unroll
  for (int r = 0; r < 16; ++r)
    Y[base + (size_t)(q0 + rbase + r) * DIM + lane] = __float2bfloat16(O[r] / l_r[r]);
}

// ---------------- host ----------------
extern "C" void kernel_launch(void* const* d_in, const int* in_sizes, int n_in,
                              void* d_out, int out_size, void* d_ws, size_t ws_size,
                              hipStream_t stream) {
  const int*   idx  = (const int*)d_in[0];
  const float* tok  = (const float*)d_in[1];
  const float* pos  = (const float*)d_in[2];
  const float* ln1g = (const float*)d_in[3];
  const float* ln1b = (const float*)d_in[4];
  const float* Wq   = (const float*)d_in[5];
  const float* bq   = (const float*)d_in[6];
  const float* Wk   = (const float*)d_in[7];
  const float* bk   = (const float*)d_in[8];
  const float* Wv   = (const float*)d_in[9];
  const float* bv   = (const float*)d_in[10];
  const float* Wo   = (const float*)d_in[11];
  const float* bo   = (const float*)d_in[12];
  const float* ln2g = (const float*)d_in[13];
  const float* ln2b = (const float*)d_in[14];
  const float* W1   = (const float*)d_in[15];
  const float* b1   = (const float*)d_in[16];
  const float* W2   = (const float*)d_in[17];
  const float* b2   = (const float*)d_in[18];
  const float* lnfg = (const float*)d_in[19];
  const float* lnfb = (const float*)d_in[20];
  const float* Wh   = (const float*)d_in[21];
  const float* bh   = (const float*)d_in[22];

  const size_t MiB = 1048576ull;
  char* wsp = (char*)d_ws;
  float* x   = (float*)(wsp + 0);            // [0,32) MiB  f32 residual
  bf16* xn   = (bf16*)(wsp + 32 * MiB);      // [32,48)  ln-out / attn-out
  bf16* qb   = (bf16*)(wsp + 48 * MiB);      // [48,64)  Q
  bf16* kbuf = (bf16*)(wsp + 64 * MiB);      // [64,80)  K
  bf16* vbuf = (bf16*)(wsp + 80 * MiB);      // [80,96)  V
  bf16* hb   = (bf16*)(wsp + 64 * MiB);      // [64,96)  FFN hidden chunk (overlays K/V, dead then)
  bf16* wb   = (bf16*)(wsp + 96 * MiB);      // [96,120) per-layer bf16 weights
  bf16* whb  = (bf16*)(wsp + 48 * MiB);      // [48,52)  head weight bf16 (overlays Q, dead then)

  const size_t M1 = 1048576ull;              // D*D
  bf16* wqb = wb;            bf16* wkb = wb + 1 * M1;
  bf16* wvb = wb + 2 * M1;   bf16* wob = wb + 3 * M1;
  bf16* w1b = wb + 4 * M1;   bf16* w2b = wb + 8 * M1;

  dim3 blk(256);
  dim3 gD(DIM / 128, NTOK / 128);            // (8, 64)
  dim3 gF1(2048 / 128, NTOK / 128);          // (16, 64) per FF chunk
  dim3 gV(VOCAB / 128, NTOK / 128);          // (16, 64)
  dim3 gA(T_SEQ / 64, NH, BATCH);            // (16, 16, 8)

  embed_kernel<<<NTOK, blk, 0, stream>>>(idx, tok, pos, x);
  for (int l = 0; l < NLAYER; ++l) {
    size_t wof = (size_t)l * DIM * DIM;
    size_t fof = (size_t)l * DIM * FFDIM;
    cvt_layer_kernel<<<12288, blk, 0, stream>>>(Wq + wof, Wk + wof, Wv + wof, Wo + wof,
                                                W1 + fof, W2 + fof, wb);
    ln_kernel<<<NTOK, blk, 0, stream>>>(x, ln1g + l * DIM, ln1b + l * DIM, xn);
    gemm_kernel<0><<<gD, blk, 0, stream>>>(xn, wqb, bq + l * DIM, qb, nullptr,
                                           NTOK, DIM, DIM, DIM, DIM, DIM);
    gemm_kernel<0><<<gD, blk, 0, stream>>>(xn, wkb, bk + l * DIM, kbuf, nullptr,
                                           NTOK, DIM, DIM, DIM, DIM, DIM);
    gemm_kernel<0><<<gD, blk, 0, stream>>>(xn, wvb, bv + l * DIM, vbuf, nullptr,
                                           NTOK, DIM, DIM, DIM, DIM, DIM);
    attn_kernel<<<gA, blk, 0, stream>>>(qb, kbuf, vbuf, xn);
    gemm_kernel<2><<<gD, blk, 0, stream>>>(xn, wob, bo + l * DIM, nullptr, x,
                                           NTOK, DIM, DIM, DIM, DIM, DIM);
    ln_kernel<<<NTOK, blk, 0, stream>>>(x, ln2g + l * DIM, ln2b + l * DIM, xn);
    for (int c0 = 0; c0 < FFDIM; c0 += 2048) {
      gemm_kernel<1><<<gF1, blk, 0, stream>>>(xn, w1b + c0, b1 + l * FFDIM + c0, hb, nullptr,
                                              NTOK, 2048, DIM, DIM, FFDIM, 2048);
      gemm_kernel<2><<<gD, blk, 0, stream>>>(hb, w2b + (size_t)c0 * DIM, b2 + l * DIM, nullptr, x,
                                             NTOK, DIM, 2048, 2048, DIM, DIM);
    }
  }
  ln_kernel<<<NTOK, blk, 0, stream>>>(x, lnfg, lnfb, xn);
  cvt_kernel<<<2048, blk, 0, stream>>>(Wh, whb);
  gemm_kernel<3><<<gV, blk, 0, stream>>>(xn, whb, bh, d_out, nullptr,
                                         NTOK, VOCAB, DIM, DIM, VOCAB, VOCAB);
}